// Round 13
// baseline (101.454 us; speedup 1.0000x reference)
//
#include <hip/hip_runtime.h>
#include <hip/hip_bf16.h>
#include <math.h>

#define LOG2PI_F 1.8378770664093453f

typedef int i32x4 __attribute__((ext_vector_type(4)));
typedef int i32x8 __attribute__((ext_vector_type(8)));
typedef float f32x4 __attribute__((ext_vector_type(4)));

#define M_DIM 16384
#define K_DIM 2048
#define N_DIM 2048
#define BM 128
#define BN 128
#define BK 128
#define NB_N (N_DIM / BN) /* 16 */
#define NB_M (M_DIM / BM) /* 128 */
#define LSCALE 256.0f
#define QDESCALE (1.0f / 65536.0f)
#define SCALE_ONE 0x7F7F7F7F   /* e8m0 biased 127 = 2^0 in all byte lanes */

// async global->LDS, 16B per lane. LDS dest is wave-uniform base + lane*16.
__device__ __forceinline__ void gload16(const void* g, void* l) {
    __builtin_amdgcn_global_load_lds(
        (__attribute__((address_space(1))) void*)g,
        (__attribute__((address_space(3))) void*)l, 16, 0, 0);
}

// pack 4 floats -> 4 e4m3 bytes (HW RNE+sat, OCP on gfx950)
__device__ __forceinline__ unsigned int pk4_fp8(float a, float b, float c, float d) {
    unsigned int w = (unsigned int)__builtin_amdgcn_cvt_pk_fp8_f32(a, b, 0, false);
    w = (unsigned int)__builtin_amdgcn_cvt_pk_fp8_f32(c, d, (int)w, true);
    return w;
}

// ---------------------------------------------------------------------------
// Build Lq[j][i] = fp8(256 * L[i][j]) + partial sums of strict-lower Woff^2
// (ss computed from f32 BEFORE quantization -> trace_cov stays exact).
// ---------------------------------------------------------------------------
__global__ __launch_bounds__(256) void build_Lt(const float* __restrict__ Woff,
                                                const float* __restrict__ Wld,
                                                unsigned char* __restrict__ Lq,
                                                float* __restrict__ misc_arr) {
    __shared__ float tile[64][65];
    __shared__ float red[4];
    const int jt = blockIdx.x * 64;
    const int it = blockIdx.y * 64;
    const int tid = threadIdx.x;
    float ss = 0.f;

    if (it + 63 >= jt) {
        for (int e = tid; e < 4096; e += 256) {
            int r = e >> 6, c = e & 63;
            tile[r][c] = Woff[(size_t)(it + r) * K_DIM + (jt + c)];
        }
    }
    __syncthreads();

    for (int e = tid; e < 4096; e += 256) {
        int jr = e >> 6, ic = e & 63;
        int i = it + ic, j = jt + jr;
        float v = 0.f;
        if (i > j) {
            v = tile[ic][jr];
            ss += v * v;
        } else if (i == j) {
            v = expf(Wld[i]);
        }
        unsigned int w = (unsigned int)__builtin_amdgcn_cvt_pk_fp8_f32(v * LSCALE, 0.f, 0, false);
        Lq[(size_t)j * K_DIM + i] = (unsigned char)(w & 0xffu);
    }

    #pragma unroll
    for (int off = 32; off; off >>= 1) ss += __shfl_down(ss, off);
    if ((tid & 63) == 0) red[tid >> 6] = ss;
    __syncthreads();
    if (tid == 0)
        misc_arr[blockIdx.y * 32 + blockIdx.x] = red[0] + red[1] + red[2] + red[3];
}

// ---------------------------------------------------------------------------
// Cast x -> fp8 e4m3 and fuse pred_mean GEMV u[b] = dot(x[b], W_mean).
// ---------------------------------------------------------------------------
__global__ __launch_bounds__(256) void prep_x(const float* __restrict__ X,
                                              const float* __restrict__ Wm,
                                              unsigned char* __restrict__ Xq,
                                              float* __restrict__ U) {
    const int b = blockIdx.x;
    const int tid = threadIdx.x;
    const float* xr = X + (size_t)b * K_DIM;
    unsigned char* xo = Xq + (size_t)b * K_DIM;
    __shared__ float red[4];
    const int base = tid * 8;
    float4 v0 = *(const float4*)(xr + base);
    float4 v1 = *(const float4*)(xr + base + 4);
    float4 w0 = *(const float4*)(Wm + base);
    float4 w1 = *(const float4*)(Wm + base + 4);
    float dot = v0.x * w0.x + v0.y * w0.y + v0.z * w0.z + v0.w * w0.w
              + v1.x * w1.x + v1.y * w1.y + v1.z * w1.z + v1.w * w1.w;
    uint2 p;
    p.x = pk4_fp8(v0.x, v0.y, v0.z, v0.w);
    p.y = pk4_fp8(v1.x, v1.y, v1.z, v1.w);
    *(uint2*)(xo + base) = p;
    #pragma unroll
    for (int off = 32; off; off >>= 1) dot += __shfl_down(dot, off);
    if ((tid & 63) == 0) red[tid >> 6] = dot;
    __syncthreads();
    if (tid == 0) U[b] = red[0] + red[1] + red[2] + red[3];
}

// ---------------------------------------------------------------------------
// quad_gemm fp8 MX 128x128, BK=128, 2-buf LDS (64 KB), 4 waves (2M x 2N),
// __launch_bounds__(256,2) -> TWO blocks per CU. Each SIMD hosts one wave
// from each block (independent barrier domains, uncorrelated phases):
// while one block waits (lgkm/vmcnt/barrier) the other feeds the matrix
// pipe -- LDS/MFMA overlap across blocks, so the schedule is the minimal
// race-free form: ONE vmcnt + ONE barrier per K128-unit.
//   unit t: stage all of t+1 -> nbuf | read 16 b128 frags | 16 MXMFMA |
//           vmcnt(0) | s_barrier
// (frag reads of buf cur complete before the barrier because MFMA consumed
// them; staging targets nbuf only -> no WAR hazard.)
// LDS rows 128 B; 16B-chunk XOR swizzle c^=(row&7) (conflict-free b128),
// source pre-swizzled involutively. MFMA: mfma_scale 16x16x128 unit scales
// (exact fp8 GEMM, 2x rate). A,B share frag128 -> k-permutation cancels.
// Pairing (jp, 15-jp): NT sums to 17; 1024 blocks = 2 balanced rounds of
// 512 CU-slots.
// ---------------------------------------------------------------------------
__device__ __forceinline__ i32x8 frag128(const unsigned char* base, int roff, int g) {
    const unsigned char* rb = base + roff * 128;
    int x = (roff & 7) << 4;
    i32x4 lo = *(const i32x4*)(rb + (((g * 2) << 4) ^ x));
    i32x4 hi = *(const i32x4*)(rb + (((g * 2 + 1) << 4) ^ x));
    return __builtin_shufflevector(lo, hi, 0, 1, 2, 3, 4, 5, 6, 7);
}

#define MXMFMA(A, B, C) __builtin_amdgcn_mfma_scale_f32_16x16x128_f8f6f4( \
        (A), (B), (C), 0, 0, 0, SCALE_ONE, 0, SCALE_ONE)

#define BAR() asm volatile("s_barrier" ::: "memory")

__global__ __launch_bounds__(256, 2) void quad_gemm(const unsigned char* __restrict__ Xq,
                                                    const unsigned char* __restrict__ Lq,
                                                    float* __restrict__ qpart) {
    __shared__ unsigned char As[2][BM * BK];   // 2 x 16 KB
    __shared__ unsigned char Bs[2][BN * BK];   // 2 x 16 KB (64 KB total)

    const int mb = blockIdx.x;
    const int jp = blockIdx.y;              // 0..7
    const int tid = threadIdx.x;
    const int lane = tid & 63;
    const int wid = tid >> 6;               // 0..3
    const int wr = wid >> 1, wc = wid & 1;  // 2M x 2N wave grid
    const int g = lane >> 4, r16 = lane & 15;
    const int brow = mb * BM;

    // staging lane geometry: per gload16 a wave covers 8 rows x 8 chunks.
    const int srow = lane >> 3;             // 0..7 == (lds row & 7)
    const int scol = (lane & 7) ^ srow;     // pre-swizzled 16B source chunk

    auto gemm_one = [&](int nb) {
        const int bcol = nb * BN;
        const int NT = (K_DIM - bcol) >> 7;   // 16 - nb, in [1,16]

        // wave wid stages rows wid*32 + j*8 + srow (j=0..3) of each tile.
        const unsigned char* pA =
            Xq + (size_t)(brow + wid * 32 + srow) * K_DIM + bcol + scol * 16;
        const unsigned char* pB =
            Lq + (size_t)(bcol + wid * 32 + srow) * K_DIM + bcol + scol * 16;

        auto stage = [&](int t, int buf) {
            const unsigned char* sa = pA + (size_t)t * 128;
            const unsigned char* sb = pB + (size_t)t * 128;
            char* da = (char*)As[buf] + wid * 4096;
            char* db = (char*)Bs[buf] + wid * 4096;
            #pragma unroll
            for (int j = 0; j < 4; ++j) {
                gload16(sa + (size_t)(j * 8) * K_DIM, da + j * 1024);
                gload16(sb + (size_t)(j * 8) * K_DIM, db + j * 1024);
            }
        };

        f32x4 acc[4][4];
        const f32x4 zero = {0.f, 0.f, 0.f, 0.f};
        #pragma unroll
        for (int m = 0; m < 4; ++m)
            #pragma unroll
            for (int n = 0; n < 4; ++n) acc[m][n] = zero;

        // prologue: unit 0 -> buf 0
        stage(0, 0);
        asm volatile("s_waitcnt vmcnt(0)" ::: "memory");
        BAR();

        for (int t = 0; t < NT; ++t) {
            const int cur = t & 1, nbuf = cur ^ 1;
            const unsigned char* Ab = As[cur];
            const unsigned char* Bb = Bs[cur];
            const bool s1 = (t + 1 < NT);
            if (s1) stage(t + 1, nbuf);

            i32x8 af[4], bf[4];
            #pragma unroll
            for (int n = 0; n < 4; ++n) bf[n] = frag128(Bb, wc * 64 + n * 16 + r16, g);
            #pragma unroll
            for (int m = 0; m < 4; ++m) af[m] = frag128(Ab, wr * 64 + m * 16 + r16, g);

            __builtin_amdgcn_s_setprio(1);
            #pragma unroll
            for (int m = 0; m < 4; ++m)
                #pragma unroll
                for (int n = 0; n < 4; ++n)
                    acc[m][n] = MXMFMA(af[m], bf[n], acc[m][n]);
            __builtin_amdgcn_s_setprio(0);

            if (s1)
                asm volatile("s_waitcnt vmcnt(0)" ::: "memory");  // t+1 landed
            BAR();
        }

        // epilogue: per-row sum of squares over this block's 128 cols.
        // C/D: col = wc*64 + n*16 + r16, row = wr*64 + m*16 + g*4 + r
        float* qbuf = (float*)&As[0][0];  // 1 KB scratch (staging drained)
        __syncthreads();
        #pragma unroll
        for (int m = 0; m < 4; ++m) {
            #pragma unroll
            for (int r = 0; r < 4; ++r) {
                float s = 0.f;
                #pragma unroll
                for (int n = 0; n < 4; ++n) {
                    float t = acc[m][n][r];
                    s += t * t;
                }
                #pragma unroll
                for (int off = 1; off < 16; off <<= 1) s += __shfl_xor(s, off);
                if (r16 == 0) qbuf[wc * 128 + wr * 64 + m * 16 + g * 4 + r] = s;
            }
        }
        __syncthreads();
        if (tid < BM)
            qpart[(size_t)(brow + tid) * NB_N + nb] =
                (qbuf[tid] + qbuf[128 + tid]) * QDESCALE;
        __syncthreads();  // qbuf reads done before next gemm restages As[0]
    };

    gemm_one(jp);         // heavy: NT = 16 - jp  (9..16)
    gemm_one(15 - jp);    // light: NT = 1 + jp   (1..8); sum = 17 always
}
#undef BAR

// ---------------------------------------------------------------------------
// row_part: 32-block partial reduction of the per-row weighted ELBO terms.
// ---------------------------------------------------------------------------
__global__ __launch_bounds__(256) void row_part(const float* __restrict__ Y,
                                                const float* __restrict__ Cnt,
                                                const float* __restrict__ nld_p,
                                                const float* __restrict__ U,
                                                const float* __restrict__ qpart,
                                                double* __restrict__ dpart) {
    const int tid = threadIdx.x;
    const float nld = nld_p[0];
    const float inv_sig = expf(-nld);
    const float nprec = inv_sig * inv_sig;
    double s1 = 0.0, s2 = 0.0;
    const int base = blockIdx.x * 512;
    #pragma unroll
    for (int j = 0; j < 2; ++j) {
        int b = base + j * 256 + tid;
        float c = Cnt[b];
        const float4* qp = (const float4*)(qpart + (size_t)b * NB_N);
        float q = 0.f;
        #pragma unroll
        for (int v4 = 0; v4 < 4; ++v4) {
            float4 qv = qp[v4];
            q += qv.x + qv.y + qv.z + qv.w;
        }
        float d = (Y[b] - U[b]) * inv_sig;
        float pl = -0.5f * d * d - nld - 0.5f * LOG2PI_F;
        float tt = 0.5f * q * c * c * nprec;
        s1 += (double)c;
        s2 += (double)((pl - tt) * c);
    }
    __shared__ double red[2][4];
    #pragma unroll
    for (int off = 32; off; off >>= 1) {
        s1 += __shfl_down(s1, off);
        s2 += __shfl_down(s2, off);
    }
    if ((tid & 63) == 0) { red[0][tid >> 6] = s1; red[1][tid >> 6] = s2; }
    __syncthreads();
    if (tid == 0) {
        dpart[blockIdx.x * 2 + 0] = red[0][0] + red[0][1] + red[0][2] + red[0][3];
        dpart[blockIdx.x * 2 + 1] = red[1][0] + red[1][1] + red[1][2] + red[1][3];
    }
}

// ---------------------------------------------------------------------------
// finalize2: combine partials + KL/wishart scalar terms. One block.
// ---------------------------------------------------------------------------
__global__ __launch_bounds__(256) void finalize2(const float* __restrict__ nld_p,
                                                 const float* __restrict__ Wm,
                                                 const float* __restrict__ Wld,
                                                 const double* __restrict__ dpart,
                                                 const float* __restrict__ misc_arr,
                                                 float* __restrict__ out) {
    const int tid = threadIdx.x;
    const float nld = nld_p[0];
    const float inv_sig = expf(-nld);
    const float nprec = inv_sig * inv_sig;

    double s1 = 0.0, s2 = 0.0;
    if (tid < 32) { s1 = dpart[tid * 2]; s2 = dpart[tid * 2 + 1]; }

    double wm2 = 0.0, tcd = 0.0, wls = 0.0, offs = 0.0;
    for (int i = tid; i < K_DIM; i += 256) {
        float w = Wm[i];
        wm2 += (double)w * (double)w;
        float ld = Wld[i];
        tcd += exp(2.0 * (double)ld);
        wls += (double)ld;
    }
    for (int i = tid; i < 1024; i += 256) offs += (double)misc_arr[i];

    __shared__ double red[6][4];
    double vals[6] = {s1, s2, wm2, tcd, wls, offs};
    #pragma unroll
    for (int s = 0; s < 6; ++s) {
        double v = vals[s];
        #pragma unroll
        for (int off = 32; off; off >>= 1) v += __shfl_down(v, off);
        if ((tid & 63) == 0) red[s][tid >> 6] = v;
    }
    __syncthreads();
    if (tid == 0) {
        double S1 = red[0][0] + red[0][1] + red[0][2] + red[0][3];
        double S2 = red[1][0] + red[1][1] + red[1][2] + red[1][3];
        double MSE = red[2][0] + red[2][1] + red[2][2] + red[2][3];
        double TCD = red[3][0] + red[3][1] + red[3][2] + red[3][3];
        double WLS = red[4][0] + red[4][1] + red[4][2] + red[4][3];
        double OFFS = red[5][0] + red[5][1] + red[5][2] + red[5][3];

        double trace_cov = OFFS + TCD;                   // sum(L*L)
        double kl = 0.5 * (MSE + trace_cov - 2.0 * WLS); // prior_scale=1
        double wish = 1.5 * (-2.0 * (double)nld) - 0.005 * (double)nprec;
        double elbo = S2 / S1 + 1e-4 * (wish - kl);
        out[0] = (float)(-elbo);
    }
}

// ---------------------------------------------------------------------------
extern "C" void kernel_launch(void* const* d_in, const int* in_sizes, int n_in,
                              void* d_out, int out_size, void* d_ws, size_t ws_size,
                              hipStream_t stream) {
    const float* x    = (const float*)d_in[0];
    const float* y    = (const float*)d_in[1];
    const float* cnt  = (const float*)d_in[2];
    // d_in[3] = noise_mean (unused by the reference math)
    const float* nld  = (const float*)d_in[4];
    const float* Wm   = (const float*)d_in[5];
    const float* Wld  = (const float*)d_in[6];
    const float* Woff = (const float*)d_in[7];

    char* ws = (char*)d_ws;
    unsigned char* Xq = (unsigned char*)(ws);              // 16384*2048 = 33554432
    unsigned char* Lq = (unsigned char*)(ws + 33554432);   // 2048*2048  =  4194304
    double* dpart  = (double*)(ws + 40000000);             // 512 B
    float*  U      = (float*)(ws + 75497472);              // 16384*4
    float*  qpart  = (float*)(ws + 75563008);              // 16384*16*4 = 1 MB
    float*  misc   = (float*)(ws + 76611584);              // 1024*4

    build_Lt<<<dim3(32, 32), 256, 0, stream>>>(Woff, Wld, Lq, misc);
    prep_x<<<dim3(M_DIM), 256, 0, stream>>>(x, Wm, Xq, U);
    quad_gemm<<<dim3(NB_M, 8), 256, 0, stream>>>(Xq, Lq, qpart);
    row_part<<<dim3(32), 256, 0, stream>>>(y, cnt, nld, U, qpart, dpart);
    finalize2<<<1, 256, 0, stream>>>(nld, Wm, Wld, dpart, misc, (float*)d_out);
}

// Round 14
// 87.685 us; speedup vs baseline: 1.1570x; 1.1570x over previous
//
#include <hip/hip_runtime.h>
#include <hip/hip_bf16.h>
#include <math.h>

#define LOG2PI_F 1.8378770664093453f

typedef int i32x4 __attribute__((ext_vector_type(4)));
typedef int i32x8 __attribute__((ext_vector_type(8)));
typedef float f32x4 __attribute__((ext_vector_type(4)));

#define M_DIM 16384
#define K_DIM 2048
#define N_DIM 2048
#define BM 256
#define BN 256
#define BK 128
#define NB_N (N_DIM / BN) /* 8 */
#define NB_M (M_DIM / BM) /* 64 */
#define LSCALE 256.0f
#define QDESCALE (1.0f / 65536.0f)
#define SCALE_ONE 0x7F7F7F7F   /* e8m0 biased 127 = 2^0 in all byte lanes */

// async global->LDS, 16B per lane. LDS dest is wave-uniform base + lane*16.
__device__ __forceinline__ void gload16(const void* g, void* l) {
    __builtin_amdgcn_global_load_lds(
        (__attribute__((address_space(1))) void*)g,
        (__attribute__((address_space(3))) void*)l, 16, 0, 0);
}

// pack 4 floats -> 4 e4m3 bytes (HW RNE+sat, OCP on gfx950)
__device__ __forceinline__ unsigned int pk4_fp8(float a, float b, float c, float d) {
    unsigned int w = (unsigned int)__builtin_amdgcn_cvt_pk_fp8_f32(a, b, 0, false);
    w = (unsigned int)__builtin_amdgcn_cvt_pk_fp8_f32(c, d, (int)w, true);
    return w;
}

// ---------------------------------------------------------------------------
// prep_fused: blocks [0,1024) build Lq (fp8 L^T, scaled x256) + Woff^2
// partials; blocks [1024, 1024+16384) cast X->fp8 and compute the
// pred_mean GEMV. The two jobs are independent -> they run CONCURRENTLY
// in one launch (build's ~5us hides under prep's memory-bound ~30us).
// ---------------------------------------------------------------------------
__global__ __launch_bounds__(256) void prep_fused(const float* __restrict__ X,
                                                  const float* __restrict__ Wm,
                                                  const float* __restrict__ Woff,
                                                  const float* __restrict__ Wld,
                                                  unsigned char* __restrict__ Xq,
                                                  unsigned char* __restrict__ Lq,
                                                  float* __restrict__ U,
                                                  float* __restrict__ misc_arr) {
    __shared__ float tile[64][65];
    __shared__ float red[4];
    const int bid = blockIdx.x;
    const int tid = threadIdx.x;

    if (bid < 1024) {
        // ---- build_Lt: Lq[j][i] = fp8(256 * L[i][j]); ss from f32 (exact).
        const int jt = (bid & 31) * 64;
        const int it = (bid >> 5) * 64;
        float ss = 0.f;

        if (it + 63 >= jt) {
            for (int e = tid; e < 4096; e += 256) {
                int r = e >> 6, c = e & 63;
                tile[r][c] = Woff[(size_t)(it + r) * K_DIM + (jt + c)];
            }
        }
        __syncthreads();

        for (int e = tid; e < 4096; e += 256) {
            int jr = e >> 6, ic = e & 63;
            int i = it + ic, j = jt + jr;
            float v = 0.f;
            if (i > j) {
                v = tile[ic][jr];
                ss += v * v;
            } else if (i == j) {
                v = expf(Wld[i]);
            }
            unsigned int w = (unsigned int)__builtin_amdgcn_cvt_pk_fp8_f32(v * LSCALE, 0.f, 0, false);
            Lq[(size_t)j * K_DIM + i] = (unsigned char)(w & 0xffu);
        }

        #pragma unroll
        for (int off = 32; off; off >>= 1) ss += __shfl_down(ss, off);
        if ((tid & 63) == 0) red[tid >> 6] = ss;
        __syncthreads();
        if (tid == 0)
            misc_arr[bid] = red[0] + red[1] + red[2] + red[3];
    } else {
        // ---- prep_x: one row per block.
        const int b = bid - 1024;
        const float* xr = X + (size_t)b * K_DIM;
        unsigned char* xo = Xq + (size_t)b * K_DIM;
        const int base = tid * 8;
        float4 v0 = *(const float4*)(xr + base);
        float4 v1 = *(const float4*)(xr + base + 4);
        float4 w0 = *(const float4*)(Wm + base);
        float4 w1 = *(const float4*)(Wm + base + 4);
        float dot = v0.x * w0.x + v0.y * w0.y + v0.z * w0.z + v0.w * w0.w
                  + v1.x * w1.x + v1.y * w1.y + v1.z * w1.z + v1.w * w1.w;
        uint2 p;
        p.x = pk4_fp8(v0.x, v0.y, v0.z, v0.w);
        p.y = pk4_fp8(v1.x, v1.y, v1.z, v1.w);
        *(uint2*)(xo + base) = p;
        #pragma unroll
        for (int off = 32; off; off >>= 1) dot += __shfl_down(dot, off);
        if ((tid & 63) == 0) red[tid >> 6] = dot;
        __syncthreads();
        if (tid == 0) U[b] = red[0] + red[1] + red[2] + red[3];
    }
}

// ---------------------------------------------------------------------------
// quad_gemm fp8 MX 256x256, BK=128, 2-buf LDS (128 KB), 8 waves (2M x 4N).
// (unchanged from R12 -- measured best: total 98.1us, absmax 0.0)
// MFMA: mfma_scale_f32_16x16x128_f8f6f4 with unit scales (exact fp8 GEMM at
// 2x the 16x16x32 rate, 1/4 the instruction count). A and B frags both use
// frag128 (identical lane->k mapping), so any HW k-permutation cancels.
// LDS rows 128 B; 16B-chunk XOR swizzle c^=(row&7); source pre-swizzled
// involutively (gload16-compatible).
// ---------------------------------------------------------------------------
__device__ __forceinline__ i32x8 frag128(const unsigned char* base, int roff, int g) {
    const unsigned char* rb = base + roff * 128;
    int x = (roff & 7) << 4;
    i32x4 lo = *(const i32x4*)(rb + (((g * 2) << 4) ^ x));
    i32x4 hi = *(const i32x4*)(rb + (((g * 2 + 1) << 4) ^ x));
    return __builtin_shufflevector(lo, hi, 0, 1, 2, 3, 4, 5, 6, 7);
}

#define MXMFMA(A, B, C) __builtin_amdgcn_mfma_scale_f32_16x16x128_f8f6f4( \
        (A), (B), (C), 0, 0, 0, SCALE_ONE, 0, SCALE_ONE)

#define BAR() asm volatile("s_barrier" ::: "memory")
#define WAITL() { asm volatile("s_waitcnt lgkmcnt(0)" ::: "memory"); \
                  __builtin_amdgcn_sched_barrier(0); }

__global__ __launch_bounds__(512, 2) void quad_gemm(const unsigned char* __restrict__ Xq,
                                                    const unsigned char* __restrict__ Lq,
                                                    float* __restrict__ qpart) {
    __shared__ unsigned char As[2][BM * BK];   // 2 x 32 KB
    __shared__ unsigned char Bs[2][BN * BK];   // 2 x 32 KB (128 KB total)

    const int mb = blockIdx.x;
    const int jp = blockIdx.y;              // 0..3
    const int tid = threadIdx.x;
    const int lane = tid & 63;
    const int wid = tid >> 6;               // 0..7
    const int wr = wid >> 2, wc = wid & 3;  // 2M x 4N wave grid
    const int g = lane >> 4, r16 = lane & 15;
    const int brow = mb * BM;

    // staging lane geometry: per gload16 a wave covers 8 rows x 8 chunks.
    const int srow = lane >> 3;             // 0..7 == (lds row & 7)
    const int scol = (lane & 7) ^ srow;     // pre-swizzled 16B source chunk

    auto gemm_one = [&](int nb) {
        const int bcol = nb * BN;
        const int NT = (K_DIM - bcol) >> 7;   // 16 - 2*nb, in [2,16]

        const unsigned char* pA[2];
        const unsigned char* pB[2];
        #pragma unroll
        for (int h = 0; h < 2; ++h) {
            pA[h] = Xq + (size_t)(brow + h * 128 + wid * 16 + srow) * K_DIM + bcol + scol * 16;
            pB[h] = Lq + (size_t)(bcol + h * 128 + wid * 16 + srow) * K_DIM + bcol + scol * 16;
        }

        auto stgA = [&](int t, int h, int buf) {
            const unsigned char* s = pA[h] + (size_t)t * 128;
            char* d = (char*)As[buf] + h * 16384 + wid * 2048;
            gload16(s, d);
            gload16(s + (size_t)8 * K_DIM, d + 1024);
        };
        auto stgB = [&](int t, int h, int buf) {
            const unsigned char* s = pB[h] + (size_t)t * 128;
            char* d = (char*)Bs[buf] + h * 16384 + wid * 2048;
            gload16(s, d);
            gload16(s + (size_t)8 * K_DIM, d + 1024);
        };

        f32x4 acc[8][4];
        const f32x4 zero = {0.f, 0.f, 0.f, 0.f};
        #pragma unroll
        for (int m = 0; m < 8; ++m)
            #pragma unroll
            for (int n = 0; n < 4; ++n) acc[m][n] = zero;

        // prologue: A(0),B(0)->buf0 [8 loads], B(1)->buf1 [4 loads];
        // vmcnt(4) retires exactly unit 0, leaves B(1) in flight.
        stgA(0, 0, 0); stgA(0, 1, 0); stgB(0, 0, 0); stgB(0, 1, 0);
        stgB(1, 0, 1); stgB(1, 1, 1);
        asm volatile("s_waitcnt vmcnt(4)" ::: "memory");
        BAR();

        for (int t = 0; t < NT; ++t) {
            const int cur = t & 1, nbuf = cur ^ 1;
            const unsigned char* Abase = As[cur] + wr * 16384;              // 128 rows
            const unsigned char* Bbase = Bs[cur] + (wc >> 1) * 16384;       // half sel
            const int brow2 = (wc & 1) * 64;                                // row-in-half
            const bool s1 = (t + 1 < NT), s2 = (t + 2 < NT);
            i32x8 bf[4], af[4];

            // ---- ph0: B frags + A.m0-3 | stage A(t+1)->nbuf
            #pragma unroll
            for (int n = 0; n < 4; ++n) bf[n] = frag128(Bbase, brow2 + n * 16 + r16, g);
            #pragma unroll
            for (int m = 0; m < 4; ++m) af[m] = frag128(Abase, m * 16 + r16, g);
            if (s1) { stgA(t + 1, 0, nbuf); stgA(t + 1, 1, nbuf); }
            BAR();
            WAITL();
            __builtin_amdgcn_s_setprio(1);
            #pragma unroll
            for (int m = 0; m < 4; ++m)
                #pragma unroll
                for (int n = 0; n < 4; ++n)
                    acc[m][n] = MXMFMA(af[m], bf[n], acc[m][n]);
            __builtin_amdgcn_s_setprio(0);
            BAR();

            // ---- ph1: A.m4-7 | stage B(t+2)->cur (B reads done at ph0 bar)
            #pragma unroll
            for (int m = 0; m < 4; ++m) af[m] = frag128(Abase, 64 + m * 16 + r16, g);
            if (s2) { stgB(t + 2, 0, cur); stgB(t + 2, 1, cur); }
            BAR();
            WAITL();
            __builtin_amdgcn_s_setprio(1);
            #pragma unroll
            for (int m = 0; m < 4; ++m)
                #pragma unroll
                for (int n = 0; n < 4; ++n)
                    acc[4 + m][n] = MXMFMA(af[m], bf[n], acc[4 + m][n]);
            __builtin_amdgcn_s_setprio(0);

            // ---- unit end: counted wait (tail drains)
            if (s2)
                asm volatile("s_waitcnt vmcnt(4)" ::: "memory");
            else if (s1)
                asm volatile("s_waitcnt vmcnt(0)" ::: "memory");
            BAR();
        }

        // epilogue: per-row sum of squares over 256 cols, descaled by 2^-16.
        // C/D (shape-determined): col = wc*64+n*16+r16, row = wr*128+m*16+g*4+r
        float* qbuf = (float*)&As[0][0];  // 4 KB scratch (staging drained)
        __syncthreads();
        #pragma unroll
        for (int m = 0; m < 8; ++m) {
            #pragma unroll
            for (int r = 0; r < 4; ++r) {
                float s = 0.f;
                #pragma unroll
                for (int n = 0; n < 4; ++n) {
                    float t = acc[m][n][r];
                    s += t * t;
                }
                #pragma unroll
                for (int off = 1; off < 16; off <<= 1) s += __shfl_xor(s, off);
                if (r16 == 0) qbuf[wc * 256 + wr * 128 + m * 16 + g * 4 + r] = s;
            }
        }
        __syncthreads();
        if (tid < BM)
            qpart[(size_t)(brow + tid) * NB_N + nb] =
                (qbuf[tid] + qbuf[256 + tid] + qbuf[512 + tid] + qbuf[768 + tid]) * QDESCALE;
        __syncthreads();  // qbuf reads done before next gemm restages As[0]
    };

    gemm_one(jp);        // heavy: NT = 16 - 2*jp  (10..16)
    gemm_one(7 - jp);    // light: NT = 2 + 2*jp   (2..8); sum = 18 always
}
#undef BAR
#undef WAITL

// ---------------------------------------------------------------------------
// row_part: 32-block partial reduction of the per-row weighted ELBO terms.
// ---------------------------------------------------------------------------
__global__ __launch_bounds__(256) void row_part(const float* __restrict__ Y,
                                                const float* __restrict__ Cnt,
                                                const float* __restrict__ nld_p,
                                                const float* __restrict__ U,
                                                const float* __restrict__ qpart,
                                                double* __restrict__ dpart) {
    const int tid = threadIdx.x;
    const float nld = nld_p[0];
    const float inv_sig = expf(-nld);
    const float nprec = inv_sig * inv_sig;
    double s1 = 0.0, s2 = 0.0;
    const int base = blockIdx.x * 512;
    #pragma unroll
    for (int j = 0; j < 2; ++j) {
        int b = base + j * 256 + tid;
        float c = Cnt[b];
        const float4* qp = (const float4*)(qpart + (size_t)b * NB_N);
        float4 q0 = qp[0], q1 = qp[1];
        float q = q0.x + q0.y + q0.z + q0.w + q1.x + q1.y + q1.z + q1.w;
        float d = (Y[b] - U[b]) * inv_sig;
        float pl = -0.5f * d * d - nld - 0.5f * LOG2PI_F;
        float tt = 0.5f * q * c * c * nprec;
        s1 += (double)c;
        s2 += (double)((pl - tt) * c);
    }
    __shared__ double red[2][4];
    #pragma unroll
    for (int off = 32; off; off >>= 1) {
        s1 += __shfl_down(s1, off);
        s2 += __shfl_down(s2, off);
    }
    if ((tid & 63) == 0) { red[0][tid >> 6] = s1; red[1][tid >> 6] = s2; }
    __syncthreads();
    if (tid == 0) {
        dpart[blockIdx.x * 2 + 0] = red[0][0] + red[0][1] + red[0][2] + red[0][3];
        dpart[blockIdx.x * 2 + 1] = red[1][0] + red[1][1] + red[1][2] + red[1][3];
    }
}

// ---------------------------------------------------------------------------
// finalize2: combine partials + KL/wishart scalar terms. One block.
// ---------------------------------------------------------------------------
__global__ __launch_bounds__(256) void finalize2(const float* __restrict__ nld_p,
                                                 const float* __restrict__ Wm,
                                                 const float* __restrict__ Wld,
                                                 const double* __restrict__ dpart,
                                                 const float* __restrict__ misc_arr,
                                                 float* __restrict__ out) {
    const int tid = threadIdx.x;
    const float nld = nld_p[0];
    const float inv_sig = expf(-nld);
    const float nprec = inv_sig * inv_sig;

    double s1 = 0.0, s2 = 0.0;
    if (tid < 32) { s1 = dpart[tid * 2]; s2 = dpart[tid * 2 + 1]; }

    double wm2 = 0.0, tcd = 0.0, wls = 0.0, offs = 0.0;
    for (int i = tid; i < K_DIM; i += 256) {
        float w = Wm[i];
        wm2 += (double)w * (double)w;
        float ld = Wld[i];
        tcd += exp(2.0 * (double)ld);
        wls += (double)ld;
    }
    for (int i = tid; i < 1024; i += 256) offs += (double)misc_arr[i];

    __shared__ double red[6][4];
    double vals[6] = {s1, s2, wm2, tcd, wls, offs};
    #pragma unroll
    for (int s = 0; s < 6; ++s) {
        double v = vals[s];
        #pragma unroll
        for (int off = 32; off; off >>= 1) v += __shfl_down(v, off);
        if ((tid & 63) == 0) red[s][tid >> 6] = v;
    }
    __syncthreads();
    if (tid == 0) {
        double S1 = red[0][0] + red[0][1] + red[0][2] + red[0][3];
        double S2 = red[1][0] + red[1][1] + red[1][2] + red[1][3];
        double MSE = red[2][0] + red[2][1] + red[2][2] + red[2][3];
        double TCD = red[3][0] + red[3][1] + red[3][2] + red[3][3];
        double WLS = red[4][0] + red[4][1] + red[4][2] + red[4][3];
        double OFFS = red[5][0] + red[5][1] + red[5][2] + red[5][3];

        double trace_cov = OFFS + TCD;                   // sum(L*L)
        double kl = 0.5 * (MSE + trace_cov - 2.0 * WLS); // prior_scale=1
        double wish = 1.5 * (-2.0 * (double)nld) - 0.005 * (double)nprec;
        double elbo = S2 / S1 + 1e-4 * (wish - kl);
        out[0] = (float)(-elbo);
    }
}

// ---------------------------------------------------------------------------
extern "C" void kernel_launch(void* const* d_in, const int* in_sizes, int n_in,
                              void* d_out, int out_size, void* d_ws, size_t ws_size,
                              hipStream_t stream) {
    const float* x    = (const float*)d_in[0];
    const float* y    = (const float*)d_in[1];
    const float* cnt  = (const float*)d_in[2];
    // d_in[3] = noise_mean (unused by the reference math)
    const float* nld  = (const float*)d_in[4];
    const float* Wm   = (const float*)d_in[5];
    const float* Wld  = (const float*)d_in[6];
    const float* Woff = (const float*)d_in[7];

    char* ws = (char*)d_ws;
    unsigned char* Xq = (unsigned char*)(ws);              // 16384*2048 = 33554432
    unsigned char* Lq = (unsigned char*)(ws + 33554432);   // 2048*2048  =  4194304
    double* dpart  = (double*)(ws + 40000000);             // 512 B
    float*  U      = (float*)(ws + 75497472);              // 16384*4
    float*  qpart  = (float*)(ws + 75563008);              // 16384*8*4 = 512 KB
    float*  misc   = (float*)(ws + 76611584);              // 1024*4

    prep_fused<<<dim3(1024 + M_DIM), 256, 0, stream>>>(x, Wm, Woff, Wld, Xq, Lq, U, misc);
    quad_gemm<<<dim3(NB_M, 4), 512, 0, stream>>>(Xq, Lq, qpart);
    row_part<<<dim3(32), 256, 0, stream>>>(y, cnt, nld, U, qpart, dpart);
    finalize2<<<1, 256, 0, stream>>>(nld, Wm, Wld, dpart, misc, (float*)d_out);
}